// Round 10
// baseline (142.679 us; speedup 1.0000x reference)
//
#include <hip/hip_runtime.h>

#define T_STEPS 345
#define B_SZ    128
#define IN_SZ   13
#define H_SZ    128
#define OUT_SZ  9
#define XPITCH  16
#define TPAD    384                 // padded t-extent for cur2 [t][bo]
#define NBO     (B_SZ * OUT_SZ)     // 1152
#define NCHUNK  22                  // 22*16 = 352 >= 345
#define MASK_BYTES (B_SZ * T_STEPS * 2 * 8)   // 706560, u64 [B][T][2]

// ---------------- K1: layer-1 scan, one thread per hidden neuron ----------------
// BIT-IDENTICAL FP chains to R1/R4/R6/R8 (knife-edge numerics — do not reorder).
__global__ __launch_bounds__(128, 1)
void k1_spikes(const float* __restrict__ x, const float* __restrict__ W1,
               const float* __restrict__ b1, const float* __restrict__ beta1p,
               const float* __restrict__ thr1p,
               unsigned long long* __restrict__ masks)
{
    const int b   = blockIdx.x;
    const int tid = threadIdx.x;    // 0..127 == neuron h

    __shared__ float xst[(T_STEPS + 3) * XPITCH];

    const float* xb = x + (size_t)b * (IN_SZ * T_STEPS);
    for (int i = tid; i < IN_SZ * T_STEPS; i += 128) {
        const int c = i / T_STEPS;
        const int t = i - c * T_STEPS;
        xst[t * XPITCH + c] = xb[i];
    }

    const float bt1 = fminf(fmaxf(beta1p[0], 0.0f), 1.0f);
    const float th1 = thr1p[0];

    float w1r[IN_SZ];
#pragma unroll
    for (int c = 0; c < IN_SZ; ++c) w1r[c] = W1[tid * IN_SZ + c];
    const float b1r = b1[tid];

    float mem1 = 0.0f;
    unsigned long long* mp = masks + (size_t)b * (T_STEPS * 2) + (tid >> 6);
    const bool store_lane = (tid & 63) == 0;

    __syncthreads();

    const float4* xq = (const float4*)xst;
    float4 a0 = xq[0], a1 = xq[1], a2 = xq[2]; float a3 = xst[12];
    float4 c0 = xq[4], c1 = xq[5], c2 = xq[6]; float c3 = xst[XPITCH + 12];

    int t = 0;
    for (; t < T_STEPS - 1; t += 2) {
        const float xa[IN_SZ] = { a0.x,a0.y,a0.z,a0.w, a1.x,a1.y,a1.z,a1.w,
                                  a2.x,a2.y,a2.z,a2.w, a3 };
        const float xc[IN_SZ] = { c0.x,c0.y,c0.z,c0.w, c1.x,c1.y,c1.z,c1.w,
                                  c2.x,c2.y,c2.z,c2.w, c3 };
        a0 = xq[(t+2)*4+0]; a1 = xq[(t+2)*4+1]; a2 = xq[(t+2)*4+2]; a3 = xst[(t+2)*XPITCH+12];
        c0 = xq[(t+3)*4+0]; c1 = xq[(t+3)*4+1]; c2 = xq[(t+3)*4+2]; c3 = xst[(t+3)*XPITCH+12];

        float cura = b1r, curb = b1r;
#pragma unroll
        for (int c = 0; c < IN_SZ; ++c) {
            cura = fmaf(xa[c], w1r[c], cura);
            curb = fmaf(xc[c], w1r[c], curb);
        }

        mem1 = fmaf(bt1, mem1, cura);
        const bool pa = mem1 > th1;
        const unsigned long long ma = __ballot(pa);
        mem1 = fmaf(pa ? -1.0f : 0.0f, th1, mem1);
        if (store_lane) mp[0] = ma;

        mem1 = fmaf(bt1, mem1, curb);
        const bool pb = mem1 > th1;
        const unsigned long long mb = __ballot(pb);
        mem1 = fmaf(pb ? -1.0f : 0.0f, th1, mem1);
        if (store_lane) mp[2] = mb;

        mp += 4;
    }
    {
        const float xa[IN_SZ] = { a0.x,a0.y,a0.z,a0.w, a1.x,a1.y,a1.z,a1.w,
                                  a2.x,a2.y,a2.z,a2.w, a3 };
        float cura = b1r;
#pragma unroll
        for (int c = 0; c < IN_SZ; ++c) cura = fmaf(xa[c], w1r[c], cura);
        mem1 = fmaf(bt1, mem1, cura);
        const bool pa = mem1 > th1;
        const unsigned long long ma = __ballot(pa);
        if (store_lane) mp[0] = ma;
    }
}

// ---------------- K2: cur2 GEMM, bit-masked dot (R8 verbatim) ----------------
__global__ __launch_bounds__(256, 1)
void k2_gemm(const unsigned long long* __restrict__ masks,
             const float* __restrict__ W2, const float* __restrict__ b2,
             float* __restrict__ cur2)
{
    const int gw   = blockIdx.x * 4 + (threadIdx.x >> 6);  // global wave 0..6911
    const int lane = threadIdx.x & 63;
    const int bo   = gw / 6;             // 0..1151
    const int w    = gw - bo * 6;
    const int b    = bo / 9;
    const int o    = bo - b * 9;
    const int t    = w * 64 + lane;      // 0..383
    const int tc   = (t < T_STEPS) ? t : (T_STEPS - 1);

    const uint4 mm = *(const uint4*)((const char*)masks +
                                     ((size_t)b * T_STEPS + tc) * 16);

    const float* __restrict__ w2row = W2 + o * H_SZ;
    float acc = 0.0f;
#pragma unroll
    for (int h = 0; h < 32; ++h)
        acc = fmaf((float)((mm.x >> h) & 1u), w2row[h], acc);
#pragma unroll
    for (int h = 0; h < 32; ++h)
        acc = fmaf((float)((mm.y >> h) & 1u), w2row[32 + h], acc);
#pragma unroll
    for (int h = 0; h < 32; ++h)
        acc = fmaf((float)((mm.z >> h) & 1u), w2row[64 + h], acc);
#pragma unroll
    for (int h = 0; h < 32; ++h)
        acc = fmaf((float)((mm.w >> h) & 1u), w2row[96 + h], acc);

    cur2[(size_t)t * NBO + bo] = acc + b2[o];
}

// ---------------- K3: mem2 scan — 2 blocks x 576 threads, lane = bo ----------------
// At fixed t, a block's lanes cover 576 CONSECUTIVE bo -> cur2 loads and out
// stores are fully coalesced (18 whole 128B lines per row per block), unlike
// R7-R9 where each 9-lane store covered 36 B. Scan chain per (b,o) is
// bit-identical to R7/R8/R9. 16-step chunks, double-buffered loads,
// per-parity register buffers, burst stores.
__global__ __launch_bounds__(576, 1)
void k3_scan2(const float* __restrict__ cur2, const float* __restrict__ beta2p,
              const float* __restrict__ thr2p, float* __restrict__ out)
{
    const int bo = blockIdx.x * 576 + threadIdx.x;   // 0..1151
    const float bt2 = fminf(fmaxf(beta2p[0], 0.0f), 1.0f);
    const float th2 = thr2p[0];

    const float* __restrict__ src = cur2 + bo;                   // [t][NBO]
    float* __restrict__ out_spk = out + bo;
    float* __restrict__ out_mem = out + (size_t)T_STEPS * NBO + bo;

    float mem2 = 0.0f;

    float A[16], Bb[16];
#pragma unroll
    for (int j = 0; j < 16; ++j) A[j]  = src[(size_t)j * NBO];
#pragma unroll
    for (int j = 0; j < 16; ++j) Bb[j] = src[(size_t)(16 + j) * NBO];

    float sE[16], mE[16], sO[16], mO[16];

    for (int c = 0; c < NCHUNK; c += 2) {
        // ---- even chunk c ----
#pragma unroll
        for (int j = 0; j < 16; ++j) {
            mem2 = fmaf(bt2, mem2, A[j]);
            const float sp = (mem2 > th2) ? 1.0f : 0.0f;
            mem2 = fmaf(-sp, th2, mem2);
            sE[j] = sp; mE[j] = mem2;
        }
        const int cn = (c + 2 < NCHUNK) ? (c + 2) : c;
#pragma unroll
        for (int j = 0; j < 16; ++j) A[j] = src[(size_t)(cn * 16 + j) * NBO];
        {
            const size_t base = (size_t)c * 16 * NBO;   // even c <= 20 -> t < 336
#pragma unroll
            for (int j = 0; j < 16; ++j) {
                out_spk[base + (size_t)j * NBO] = sE[j];
                out_mem[base + (size_t)j * NBO] = mE[j];
            }
        }

        // ---- odd chunk c+1 ----
#pragma unroll
        for (int j = 0; j < 16; ++j) {
            mem2 = fmaf(bt2, mem2, Bb[j]);
            const float sp = (mem2 > th2) ? 1.0f : 0.0f;
            mem2 = fmaf(-sp, th2, mem2);
            sO[j] = sp; mO[j] = mem2;
        }
        const int cn2 = (c + 3 < NCHUNK) ? (c + 3) : c;
#pragma unroll
        for (int j = 0; j < 16; ++j) Bb[j] = src[(size_t)(cn2 * 16 + j) * NBO];
        if (c + 1 < NCHUNK - 1) {
            const size_t base = (size_t)(c + 1) * 16 * NBO;
#pragma unroll
            for (int j = 0; j < 16; ++j) {
                out_spk[base + (size_t)j * NBO] = sO[j];
                out_mem[base + (size_t)j * NBO] = mO[j];
            }
        } else {
            // last chunk: t = 336..351 -> store only t < 345
            const size_t base = (size_t)(c + 1) * 16 * NBO;
#pragma unroll
            for (int j = 0; j < 9; ++j) {
                out_spk[base + (size_t)j * NBO] = sO[j];
                out_mem[base + (size_t)j * NBO] = mO[j];
            }
        }
    }
}

extern "C" void kernel_launch(void* const* d_in, const int* in_sizes, int n_in,
                              void* d_out, int out_size, void* d_ws, size_t ws_size,
                              hipStream_t stream) {
    const float* x     = (const float*)d_in[0];
    const float* W1    = (const float*)d_in[1];
    const float* b1    = (const float*)d_in[2];
    const float* W2    = (const float*)d_in[3];
    const float* b2    = (const float*)d_in[4];
    const float* beta1 = (const float*)d_in[5];
    const float* thr1  = (const float*)d_in[6];
    const float* beta2 = (const float*)d_in[7];
    const float* thr2  = (const float*)d_in[8];
    float* out = (float*)d_out;

    char* ws = (char*)d_ws;
    unsigned long long* masks = (unsigned long long*)ws;        // 706,560 B
    float* cur2 = (float*)(ws + MASK_BYTES);                    // [TPAD][NBO] = 1,769,472 B

    k1_spikes<<<dim3(B_SZ), dim3(128), 0, stream>>>(x, W1, b1, beta1, thr1, masks);
    k2_gemm  <<<dim3(1728), dim3(256), 0, stream>>>(masks, W2, b2, cur2);
    k3_scan2 <<<dim3(2), dim3(576), 0, stream>>>(cur2, beta2, thr2, out);
}

// Round 11
// 127.135 us; speedup vs baseline: 1.1223x; 1.1223x over previous
//
#include <hip/hip_runtime.h>

#define T_STEPS 345
#define B_SZ    128
#define IN_SZ   13
#define H_SZ    128
#define OUT_SZ  9
#define XPITCH  16
#define TPAD    384                 // padded t-extent for cur2 [bo][t]
#define NBO     (B_SZ * OUT_SZ)     // 1152
#define NCHUNK  22                  // 22*16 = 352 >= 345
#define MASK_BYTES (B_SZ * T_STEPS * 2 * 8)   // 706560, u64 [B][T][2]

// ---------------- K1: layer-1 scan, one thread per hidden neuron ----------------
// BYTE-IDENTICAL to R7 (wall-record config). Knife-edge FP chains — do not touch.
__global__ __launch_bounds__(128, 1)
void k1_spikes(const float* __restrict__ x, const float* __restrict__ W1,
               const float* __restrict__ b1, const float* __restrict__ beta1p,
               const float* __restrict__ thr1p,
               unsigned long long* __restrict__ masks)
{
    const int b   = blockIdx.x;
    const int tid = threadIdx.x;    // 0..127 == neuron h

    __shared__ float xst[(T_STEPS + 3) * XPITCH];

    const float* xb = x + (size_t)b * (IN_SZ * T_STEPS);
    for (int i = tid; i < IN_SZ * T_STEPS; i += 128) {
        const int c = i / T_STEPS;
        const int t = i - c * T_STEPS;
        xst[t * XPITCH + c] = xb[i];
    }

    const float bt1 = fminf(fmaxf(beta1p[0], 0.0f), 1.0f);
    const float th1 = thr1p[0];

    float w1r[IN_SZ];
#pragma unroll
    for (int c = 0; c < IN_SZ; ++c) w1r[c] = W1[tid * IN_SZ + c];
    const float b1r = b1[tid];

    float mem1 = 0.0f;
    unsigned long long* mp = masks + (size_t)b * (T_STEPS * 2) + (tid >> 6);
    const bool store_lane = (tid & 63) == 0;

    __syncthreads();

    const float4* xq = (const float4*)xst;
    float4 a0 = xq[0], a1 = xq[1], a2 = xq[2]; float a3 = xst[12];
    float4 c0 = xq[4], c1 = xq[5], c2 = xq[6]; float c3 = xst[XPITCH + 12];

    int t = 0;
    for (; t < T_STEPS - 1; t += 2) {
        const float xa[IN_SZ] = { a0.x,a0.y,a0.z,a0.w, a1.x,a1.y,a1.z,a1.w,
                                  a2.x,a2.y,a2.z,a2.w, a3 };
        const float xc[IN_SZ] = { c0.x,c0.y,c0.z,c0.w, c1.x,c1.y,c1.z,c1.w,
                                  c2.x,c2.y,c2.z,c2.w, c3 };
        a0 = xq[(t+2)*4+0]; a1 = xq[(t+2)*4+1]; a2 = xq[(t+2)*4+2]; a3 = xst[(t+2)*XPITCH+12];
        c0 = xq[(t+3)*4+0]; c1 = xq[(t+3)*4+1]; c2 = xq[(t+3)*4+2]; c3 = xst[(t+3)*XPITCH+12];

        float cura = b1r, curb = b1r;
#pragma unroll
        for (int c = 0; c < IN_SZ; ++c) {
            cura = fmaf(xa[c], w1r[c], cura);
            curb = fmaf(xc[c], w1r[c], curb);
        }

        mem1 = fmaf(bt1, mem1, cura);
        const bool pa = mem1 > th1;
        const unsigned long long ma = __ballot(pa);
        mem1 = fmaf(pa ? -1.0f : 0.0f, th1, mem1);
        if (store_lane) mp[0] = ma;

        mem1 = fmaf(bt1, mem1, curb);
        const bool pb = mem1 > th1;
        const unsigned long long mb = __ballot(pb);
        mem1 = fmaf(pb ? -1.0f : 0.0f, th1, mem1);
        if (store_lane) mp[2] = mb;

        mp += 4;
    }
    {
        const float xa[IN_SZ] = { a0.x,a0.y,a0.z,a0.w, a1.x,a1.y,a1.z,a1.w,
                                  a2.x,a2.y,a2.z,a2.w, a3 };
        float cura = b1r;
#pragma unroll
        for (int c = 0; c < IN_SZ; ++c) cura = fmaf(xa[c], w1r[c], cura);
        mem1 = fmaf(bt1, mem1, cura);
        const bool pa = mem1 > th1;
        const unsigned long long ma = __ballot(pa);
        if (store_lane) mp[0] = ma;
    }
}

// ---------------- K2: cur2 GEMM, bit-masked dot — BYTE-IDENTICAL to R7 ----------------
// Writes cur2[bo][t]: per-lane t-contiguous so K3 can dwordx4 its loads.
__global__ __launch_bounds__(256, 1)
void k2_gemm(const unsigned long long* __restrict__ masks,
             const float* __restrict__ W2, const float* __restrict__ b2,
             float* __restrict__ cur2)
{
    const int gw   = blockIdx.x * 4 + (threadIdx.x >> 6);  // global wave 0..6911
    const int lane = threadIdx.x & 63;
    const int bo   = gw / 6;             // 0..1151
    const int w    = gw - bo * 6;
    const int b    = bo / 9;
    const int o    = bo - b * 9;
    const int t    = w * 64 + lane;      // 0..383
    const int tc   = (t < T_STEPS) ? t : (T_STEPS - 1);

    const uint4 mm = *(const uint4*)((const char*)masks +
                                     ((size_t)b * T_STEPS + tc) * 16);

    const float* __restrict__ w2row = W2 + o * H_SZ;
    float acc = 0.0f;
#pragma unroll
    for (int h = 0; h < 32; ++h)
        acc = fmaf((float)((mm.x >> h) & 1u), w2row[h], acc);
#pragma unroll
    for (int h = 0; h < 32; ++h)
        acc = fmaf((float)((mm.y >> h) & 1u), w2row[32 + h], acc);
#pragma unroll
    for (int h = 0; h < 32; ++h)
        acc = fmaf((float)((mm.z >> h) & 1u), w2row[64 + h], acc);
#pragma unroll
    for (int h = 0; h < 32; ++h)
        acc = fmaf((float)((mm.w >> h) & 1u), w2row[96 + h], acc);

    cur2[(size_t)bo * TPAD + t] = acc + b2[o];
}

// ---------------- K3: mem2 scan — R7's 18x64 shape, decoupled stores ----------------
// Changes vs R7's k3 (the measured 56-us bottleneck), scan math untouched:
//  * loads: dwordx4 from [bo][t] (4 steps/instr), TRIPLE-buffered 3 chunks
//    (48 steps) ahead -> ~600 cyc of compute covers LLC/HBM load latency.
//  * stores: scan writes into parity register buffers (sE/mE vs sO/mO),
//    burst-stored after each chunk; store-source registers aren't reused for
//    2 chunks, so the per-step vmcnt round-trip R7 paid 345x becomes ~1
//    cheap wait per chunk. Stores stay 256B-coalesced (lanes = 64 consec bo).
__global__ __launch_bounds__(64, 1)
void k3_scan2(const float* __restrict__ cur2, const float* __restrict__ beta2p,
              const float* __restrict__ thr2p, float* __restrict__ out)
{
    const int lid = blockIdx.x * 64 + threadIdx.x;   // 0..1151 == b*9+o
    const float bt2 = fminf(fmaxf(beta2p[0], 0.0f), 1.0f);
    const float th2 = thr2p[0];

    const float4* __restrict__ src4 = (const float4*)(cur2 + (size_t)lid * TPAD);
    float* __restrict__ out_spk = out + lid;
    float* __restrict__ out_mem = out + (size_t)T_STEPS * NBO + lid;

    float mem2 = 0.0f;

    float4 buf[3][4];
#pragma unroll
    for (int q = 0; q < 4; ++q) buf[0][q] = src4[0 * 4 + q];
#pragma unroll
    for (int q = 0; q < 4; ++q) buf[1][q] = src4[1 * 4 + q];
#pragma unroll
    for (int q = 0; q < 4; ++q) buf[2][q] = src4[2 * 4 + q];

    float sE[16], mE[16], sO[16], mO[16];

#pragma unroll
    for (int c = 0; c < NCHUNK; ++c) {
        float* sB = (c & 1) ? sO : sE;
        float* mB = (c & 1) ? mO : mE;
        const int slot = c % 3;

        // consume 16 steps (t = 16c .. 16c+15), exact R7 order
#pragma unroll
        for (int q = 0; q < 4; ++q) {
            const float4 v4 = buf[slot][q];
            const float vv[4] = { v4.x, v4.y, v4.z, v4.w };
#pragma unroll
            for (int k = 0; k < 4; ++k) {
                mem2 = fmaf(bt2, mem2, vv[k]);
                const float sp = (mem2 > th2) ? 1.0f : 0.0f;
                mem2 = fmaf(-sp, th2, mem2);
                sB[q * 4 + k] = sp;
                mB[q * 4 + k] = mem2;
            }
        }

        // refill this slot for chunk c+3
        if (c + 3 < NCHUNK) {
#pragma unroll
            for (int q = 0; q < 4; ++q) buf[slot][q] = src4[(c + 3) * 4 + q];
        }

        // burst store this chunk (last chunk: only t < 345 -> j < 9)
        const size_t base = (size_t)c * 16 * NBO;
#pragma unroll
        for (int j = 0; j < 16; ++j) {
            if (j < ((c == NCHUNK - 1) ? 9 : 16)) {
                out_spk[base + (size_t)j * NBO] = sB[j];
                out_mem[base + (size_t)j * NBO] = mB[j];
            }
        }
    }
}

extern "C" void kernel_launch(void* const* d_in, const int* in_sizes, int n_in,
                              void* d_out, int out_size, void* d_ws, size_t ws_size,
                              hipStream_t stream) {
    const float* x     = (const float*)d_in[0];
    const float* W1    = (const float*)d_in[1];
    const float* b1    = (const float*)d_in[2];
    const float* W2    = (const float*)d_in[3];
    const float* b2    = (const float*)d_in[4];
    const float* beta1 = (const float*)d_in[5];
    const float* thr1  = (const float*)d_in[6];
    const float* beta2 = (const float*)d_in[7];
    const float* thr2  = (const float*)d_in[8];
    float* out = (float*)d_out;

    char* ws = (char*)d_ws;
    unsigned long long* masks = (unsigned long long*)ws;        // 706,560 B
    float* cur2 = (float*)(ws + MASK_BYTES);                    // [NBO][TPAD] = 1,769,472 B

    k1_spikes<<<dim3(B_SZ), dim3(128), 0, stream>>>(x, W1, b1, beta1, thr1, masks);
    k2_gemm  <<<dim3(1728), dim3(256), 0, stream>>>(masks, W2, b2, cur2);
    k3_scan2 <<<dim3(NBO / 64), dim3(64), 0, stream>>>(cur2, beta2, thr2, out);
}